// Round 11
// baseline (7379.016 us; speedup 1.0000x reference)
//
#include <hip/hip_runtime.h>
#include <hip/hip_bf16.h>

#define B_ 8
#define N_ 4096
#define K_ 16
#define D_ 128

typedef short bf16x8 __attribute__((ext_vector_type(8)));
typedef float f32x4 __attribute__((ext_vector_type(4)));
typedef unsigned long long u64;

__device__ __forceinline__ short bfr(float x){
  __hip_bfloat16 h = __float2bfloat16(x);
  return *reinterpret_cast<short*>(&h);
}

// ---------------- prep: bf16 transposed weights + zero stats ----------------
__global__ __launch_bounds__(256) void prep_kernel(
    const float* __restrict__ W1, const float* __restrict__ Wf, const float* __restrict__ cw2,
    short* __restrict__ W1T, short* __restrict__ WfT, short* __restrict__ cw2b,
    float* __restrict__ stats)
{
  int t = blockIdx.x*256 + threadIdx.x;
  if (t < 16384) {                       // W1T[d][c] = W1[c][d]
    int d = t >> 7, c = t & 127;
    W1T[t] = bfr(W1[c*128 + d]);
  } else if (t < 49152) {                // WfT[d][c] = Wf[c][d]
    int u = t - 16384;
    int d = u >> 8, c = u & 255;
    WfT[u] = bfr(Wf[c*128 + d]);
  } else if (t < 57344) {                // cw2 already [d][c] row-major
    int u = t - 49152;
    cw2b[u] = bfr(cw2[u]);
  } else if (t < 57360) {
    stats[t - 57344] = 0.0f;
  }
}

// ---------------- knn (R9 verbatim — proven green) ----------------
__device__ __forceinline__ void insert16(float (&bd)[16], int (&bi)[16], float d, int cid){
  #pragma unroll
  for (int j = 15; j >= 1; --j){
    bool ltj = d < bd[j];
    bool ltp = d < bd[j-1];
    float nd = ltj ? (ltp ? bd[j-1] : d) : bd[j];
    int   ni = ltj ? (ltp ? bi[j-1] : cid) : bi[j];
    bd[j] = nd; bi[j] = ni;
  }
  bool lt0 = d < bd[0];
  bd[0] = lt0 ? d : bd[0];
  bi[0] = lt0 ? cid : bi[0];
}

__device__ __forceinline__ void insert16t(float (&bd)[16], int (&bi)[16], float d, int cid){
  bool lt[16];
  #pragma unroll
  for (int j = 0; j < 16; ++j)
    lt[j] = (d < bd[j]) || ((d == bd[j]) && (cid < bi[j]));
  #pragma unroll
  for (int j = 15; j >= 1; --j){
    float nd = lt[j] ? (lt[j-1] ? bd[j-1] : d) : bd[j];
    int   ni = lt[j] ? (lt[j-1] ? bi[j-1] : cid) : bi[j];
    bd[j] = nd; bi[j] = ni;
  }
  if (lt[0]){ bd[0] = d; bi[0] = cid; }
}

__global__ __launch_bounds__(512) void knn_kernel(
    const float* __restrict__ xyz, int* __restrict__ idx_out, float* __restrict__ stats)
{
  __shared__ float4 cand[N_];            // 64 KB: x,y,z,|p|^2 (XOR-swizzled)
  int b    = blockIdx.x >> 6;            // 64 blocks per batch
  int qblk = (blockIdx.x & 63) << 6;     // 64 queries per block
  const float* xb = xyz + b*N_*3;
  for (int i = threadIdx.x; i < N_; i += 512){
    float x = xb[i*3+0], y = xb[i*3+1], z = xb[i*3+2];
    int e = i ^ ((i >> 9) & 7);          // swizzled slot (bijection within slice)
    cand[e] = make_float4(x, y, z, x*x + y*y + z*z);
  }
  __syncthreads();

  int wv = threadIdx.x >> 6, lane = threadIdx.x & 63;
  int q = lane & 7;                      // query within wave's 8
  int s = lane >> 3;                     // slice 0..7
  int qi = qblk + (wv << 3) + q;         // batch-local query index
  float4 qc = cand[qi ^ ((qi >> 9) & 7)];

  float bd[16]; int bi[16];
  #pragma unroll
  for (int j = 0; j < 16; ++j){ bd[j] = 3.4e38f; bi[j] = 0x7fffffff; }

  int cbase = s << 9;
  float4 cb0[4], cb1[4];
  #pragma unroll
  for (int j = 0; j < 4; ++j) cb0[j] = cand[cbase + (j ^ s)];
  for (int m = 0; m < 512; m += 4){
    int mn = (m + 4) & 511;
    #pragma unroll
    for (int j = 0; j < 4; ++j) cb1[j] = cand[cbase + ((mn + j) ^ s)];
    #pragma unroll
    for (int j = 0; j < 4; ++j){
      float4 c = cb0[j];
      float t = qc.x*c.x + qc.y*c.y + qc.z*c.z;
      float d = (qc.w + c.w) - 2.0f*t;
      if (d < bd[15]) insert16(bd, bi, d, cbase + m + j);
    }
    #pragma unroll
    for (int j = 0; j < 4; ++j) cb0[j] = cb1[j];
  }

  #pragma unroll
  for (int xm = 32; xm >= 8; xm >>= 1){
    bool absorb = (lane & xm) == 0;
    #pragma unroll
    for (int j = 0; j < 16; ++j){
      float pdj = __shfl_xor(bd[j], xm);
      int   pij = __shfl_xor(bi[j], xm);
      if (absorb) insert16t(bd, bi, pdj, pij);
    }
  }

  float sv[9];
  #pragma unroll
  for (int i = 0; i < 9; ++i) sv[i] = 0.0f;
  if (s == 0){
    int gq = b*N_ + qi;
    #pragma unroll
    for (int j = 0; j < 16; ++j){
      idx_out[gq*16 + j] = bi[j];
      int be = bi[j] ^ ((bi[j] >> 9) & 7);
      float4 c = cand[be];
      float rx = c.x - qc.x, ry = c.y - qc.y, rz = c.z - qc.z;
      sv[0] += rx;    sv[1] += ry;    sv[2] += rz;
      sv[3] += rx*rx; sv[4] += ry*ry; sv[5] += rz*rz;
      sv[6] += rx*ry; sv[7] += rx*rz; sv[8] += ry*rz;
    }
  }
  #pragma unroll
  for (int i = 0; i < 9; ++i){
    float v = sv[i];
    #pragma unroll
    for (int mask = 1; mask < 64; mask <<= 1) v += __shfl_xor(v, mask);
    if (lane == 0) atomicAdd(&stats[i], v);
  }
}

// ---------------- bitonic probe (diagnostic: WRITES NOTHING) ----------------
__device__ __forceinline__ u64 pack_key(float d, int idx){
  unsigned ub = __float_as_uint(d);
  ub ^= (unsigned)(((int)ub >> 31) | 0x80000000);
  return ((u64)ub << 32) | (unsigned)idx;
}
__device__ __forceinline__ void ce_asc(u64 &a, u64 &b){
  u64 lo = a < b ? a : b;
  u64 hi = a < b ? b : a;
  a = lo; b = hi;
}
__device__ __forceinline__ void sort16(u64 (&k)[16]){
  #pragma unroll
  for (int kk = 2; kk <= 16; kk <<= 1){
    #pragma unroll
    for (int j = kk >> 1; j > 0; j >>= 1){
      #pragma unroll
      for (int i = 0; i < 16; ++i){
        int l = i ^ j;
        if (l > i){
          if ((i & kk) == 0) ce_asc(k[i], k[l]);
          else               ce_asc(k[l], k[i]);
        }
      }
    }
  }
}
__device__ __forceinline__ void merge16(u64 (&bd)[16], const u64 (&c)[16]){
  u64 m[16];
  #pragma unroll
  for (int i = 0; i < 16; ++i)
    m[i] = bd[i] < c[15-i] ? bd[i] : c[15-i];
  #pragma unroll
  for (int j = 8; j > 0; j >>= 1){
    #pragma unroll
    for (int i = 0; i < 16; ++i){
      int l = i ^ j;
      if (l > i) ce_asc(m[i], m[l]);
    }
  }
  #pragma unroll
  for (int i = 0; i < 16; ++i) bd[i] = m[i];
}

// Recomputes selection with the bitonic path and compares vs idx_ref.
// Mismatch => long dependent-FMA spin => probe dur_us >1.5ms (binary signal).
__global__ __launch_bounds__(512) void knn_bitonic_probe(
    const float* __restrict__ xyz, const int* __restrict__ idx_ref)
{
  __shared__ float4 cand[N_];
  int b    = blockIdx.x >> 6;
  int qblk = (blockIdx.x & 63) << 6;
  const float* xb = xyz + b*N_*3;
  for (int i = threadIdx.x; i < N_; i += 512){
    float x = xb[i*3+0], y = xb[i*3+1], z = xb[i*3+2];
    int e = i ^ ((i >> 9) & 7);
    cand[e] = make_float4(x, y, z, x*x + y*y + z*z);
  }
  __syncthreads();

  int lane = threadIdx.x & 63;
  int q = lane & 7;
  int s = lane >> 3;
  int qi = qblk + ((threadIdx.x >> 6) << 3) + q;
  float4 qc = cand[qi ^ ((qi >> 9) & 7)];

  u64 bd[16];
  #pragma unroll
  for (int j = 0; j < 16; ++j) bd[j] = 0xFFFFFFFFFFFFFFFFull;

  int cbase = s << 9;
  for (int m = 0; m < 512; m += 16){
    u64 ck[16];
    #pragma unroll
    for (int j = 0; j < 16; ++j){
      float4 c = cand[cbase + ((m + j) ^ s)];
      float t = qc.x*c.x + qc.y*c.y + qc.z*c.z;
      float d = (qc.w + c.w) - 2.0f*t;
      ck[j] = pack_key(d, cbase + m + j);
    }
    sort16(ck);
    merge16(bd, ck);
  }
  #pragma unroll
  for (int xm = 8; xm <= 32; xm <<= 1){
    u64 pc[16];
    #pragma unroll
    for (int j = 0; j < 16; ++j){
      unsigned lo = __shfl_xor((unsigned)(bd[j] & 0xFFFFFFFFu), xm);
      unsigned hi = __shfl_xor((unsigned)(bd[j] >> 32), xm);
      pc[j] = ((u64)hi << 32) | lo;
    }
    merge16(bd, pc);
  }

  int mc = 0;
  if (s == 0){
    int gq = b*N_ + qi;
    #pragma unroll
    for (int j = 0; j < 16; ++j)
      mc += (idx_ref[gq*16 + j] != (int)(bd[j] & 0xFFFFFFFFu)) ? 1 : 0;
  }
  #pragma unroll
  for (int mask = 1; mask < 64; mask <<= 1) mc += __shfl_xor(mc, mask);
  int spin = (mc > 8 ? 8 : mc) * 100000;
  float accv = 1.0f;
  for (int i = 0; i < spin; ++i) accv = accv*1.0000001f + 1e-7f;
  asm volatile("" :: "v"(accv));
}

// ---------------- BN finalize ----------------
__global__ void bn_finalize_kernel(
    const float* __restrict__ stats, const float* __restrict__ cw1, const float* __restrict__ cb1,
    const float* __restrict__ bn_g, const float* __restrict__ bn_b,
    float* __restrict__ bnsc, float* __restrict__ bnsh)
{
  int o = threadIdx.x;
  if (o >= 64) return;
  const float inv = 1.0f / (float)(B_*N_*K_);
  float m1x = stats[0]*inv, m1y = stats[1]*inv, m1z = stats[2]*inv;
  float mxx = stats[3]*inv, myy = stats[4]*inv, mzz = stats[5]*inv;
  float mxy = stats[6]*inv, mxz = stats[7]*inv, myz = stats[8]*inv;
  float w0 = cw1[o*3], w1 = cw1[o*3+1], w2 = cw1[o*3+2], cb = cb1[o];
  float wm = w0*m1x + w1*m1y + w2*m1z;
  float mu = wm + cb;
  float e2 = w0*w0*mxx + w1*w1*myy + w2*w2*mzz
           + 2.0f*(w0*w1*mxy + w0*w2*mxz + w1*w2*myz)
           + 2.0f*cb*wm + cb*cb;
  float var = e2 - mu*mu;
  float sc = bn_g[o] * rsqrtf(var + 1e-5f);
  bnsc[o] = sc;
  bnsh[o] = bn_b[o] - mu*sc;
}

// ---------------- main fused kernel: 1 wave = 2 points (shared B-frags) -----
__device__ __forceinline__ void ln_silu_store(
    f32x4 (&acc)[8], const float (&pb)[8], const float (&pg)[8], const float (&pe)[8],
    short* fw, int g, int c16)
{
  float sm[4] = {0,0,0,0}, sq[4] = {0,0,0,0};
  #pragma unroll
  for (int t = 0; t < 8; ++t){
    #pragma unroll
    for (int r = 0; r < 4; ++r){
      float v = acc[t][r] + pb[t];
      acc[t][r] = v;
      sm[r] += v; sq[r] += v*v;
    }
  }
  #pragma unroll
  for (int mask = 1; mask < 16; mask <<= 1){
    #pragma unroll
    for (int r = 0; r < 4; ++r){ sm[r] += __shfl_xor(sm[r], mask); sq[r] += __shfl_xor(sq[r], mask); }
  }
  #pragma unroll
  for (int r = 0; r < 4; ++r){
    float mean = sm[r] * (1.0f/128.0f);
    float var  = sq[r]*(1.0f/128.0f) - mean*mean;
    float rstd = rsqrtf(var + 1e-5f);
    #pragma unroll
    for (int t = 0; t < 8; ++t){
      float y = (acc[t][r] - mean) * rstd * pg[t] + pe[t];
      y = y / (1.0f + __expf(-y));       // SiLU
      fw[(g*4 + r)*264 + t*16 + c16] = bfr(y);
    }
  }
}

__device__ __forceinline__ void geo_store(
    float rx, float ry, float rz,
    const float* s_cw1, const float* s_cb1, const float* s_sc, const float* s_sh,
    const short* __restrict__ cw2b, const float (&pc2)[8],
    short* fw, int g, int c16)
{
  bf16x8 a2[2];
  #pragma unroll
  for (int ks = 0; ks < 2; ++ks){
    bf16x8 v;
    #pragma unroll
    for (int j = 0; j < 8; ++j){
      int o = ks*32 + g*8 + j;
      float h = s_cw1[o*3]*rx + s_cw1[o*3+1]*ry + s_cw1[o*3+2]*rz + s_cb1[o];
      h = h * s_sc[o] + s_sh[o];
      h = h / (1.0f + __expf(-h));
      v[j] = bfr(h);
    }
    a2[ks] = v;
  }
  #pragma unroll
  for (int t = 0; t < 8; ++t){
    f32x4 a = (f32x4){0.f,0.f,0.f,0.f};
    #pragma unroll
    for (int ks = 0; ks < 2; ++ks){
      bf16x8 w = *(const bf16x8*)(cw2b + (t*16 + c16)*64 + ks*32 + g*8);
      a = __builtin_amdgcn_mfma_f32_16x16x32_bf16(a2[ks], w, a, 0, 0, 0);
    }
    #pragma unroll
    for (int r = 0; r < 4; ++r)
      fw[(g*4 + r)*264 + 128 + t*16 + c16] = bfr(a[r] + pc2[t]);
  }
}

__device__ __forceinline__ void epilogue_store(
    f32x4 (&acc)[8], const float (&pbf)[8], const float (&pgf)[8], const float (&pef)[8],
    const float (&pal)[8], const float (&pbt)[8],
    int point, int g, int c16, float* __restrict__ out)
{
  float sm[4] = {0,0,0,0}, sq[4] = {0,0,0,0};
  #pragma unroll
  for (int t = 0; t < 8; ++t){
    #pragma unroll
    for (int r = 0; r < 4; ++r){
      float v = acc[t][r] + pbf[t];
      acc[t][r] = v;
      sm[r] += v; sq[r] += v*v;
    }
  }
  #pragma unroll
  for (int mask = 1; mask < 16; mask <<= 1){
    #pragma unroll
    for (int r = 0; r < 4; ++r){ sm[r] += __shfl_xor(sm[r], mask); sq[r] += __shfl_xor(sq[r], mask); }
  }
  #pragma unroll
  for (int r = 0; r < 4; ++r){
    float mean = sm[r] * (1.0f/128.0f);
    float var  = sq[r]*(1.0f/128.0f) - mean*mean;
    float rstd = rsqrtf(var + 1e-5f);
    #pragma unroll
    for (int t = 0; t < 8; ++t){
      float y = (acc[t][r] - mean) * rstd * pgf[t] + pef[t];
      y = y / (1.0f + __expf(-y));
      acc[t][r] = pal[t]*y + pbt[t];
    }
  }
  float sr[4] = {0,0,0,0};
  #pragma unroll
  for (int t = 0; t < 8; ++t){
    #pragma unroll
    for (int r = 0; r < 4; ++r) sr[r] += acc[t][r];
  }
  #pragma unroll
  for (int mask = 1; mask < 16; mask <<= 1){
    #pragma unroll
    for (int r = 0; r < 4; ++r) sr[r] += __shfl_xor(sr[r], mask);
  }
  float mx = fmaxf(fmaxf(sr[0], sr[1]), fmaxf(sr[2], sr[3]));
  mx = fmaxf(mx, __shfl_xor(mx, 16));
  mx = fmaxf(mx, __shfl_xor(mx, 32));
  float e[4]; float se = 0.f;
  #pragma unroll
  for (int r = 0; r < 4; ++r){ e[r] = __expf(sr[r] - mx); se += e[r]; }
  se += __shfl_xor(se, 16);
  se += __shfl_xor(se, 32);
  float inv = 1.0f / se;
  #pragma unroll
  for (int r = 0; r < 4; ++r) e[r] *= inv;
  #pragma unroll
  for (int t = 0; t < 8; ++t){
    float o = e[0]*acc[t][0] + e[1]*acc[t][1] + e[2]*acc[t][2] + e[3]*acc[t][3];
    o += __shfl_xor(o, 16);
    o += __shfl_xor(o, 32);
    if (g == 0) out[point*128 + t*16 + c16] = o;
  }
}

__global__ __launch_bounds__(256) void lga_main_kernel(
    const float* __restrict__ xyz, const float* __restrict__ feats, const int* __restrict__ idx_ws,
    const short* __restrict__ W1T, const short* __restrict__ WfT, const short* __restrict__ cw2b,
    const float* __restrict__ b1, const float* __restrict__ ln1g, const float* __restrict__ ln1b,
    const float* __restrict__ cw1, const float* __restrict__ cb1,
    const float* __restrict__ bnsc, const float* __restrict__ bnsh,
    const float* __restrict__ cb2, const float* __restrict__ bfb,
    const float* __restrict__ lnfg, const float* __restrict__ lnfb,
    const float* __restrict__ alpha, const float* __restrict__ beta,
    float* __restrict__ out)
{
  __shared__ short fuse[4][16][264];     // per-wave buffer, time-shared by the 2 points
  __shared__ float s_cw1[192], s_cb1[64], s_sc[64], s_sh[64];

  int tid = threadIdx.x;
  for (int i = tid; i < 192; i += 256) s_cw1[i] = cw1[i];
  if (tid < 64){ s_cb1[tid] = cb1[tid]; s_sc[tid] = bnsc[tid]; s_sh[tid] = bnsh[tid]; }
  __syncthreads();

  int wv = tid >> 6, lane = tid & 63, g = lane >> 4, c16 = lane & 15;
  int pA = blockIdx.x*8 + wv*2;
  int pB = pA + 1;
  int bbA = pA >> 12, nAi = pA & 4095;
  int bbB = pB >> 12, nBi = pB & 4095;

  int nbA = idx_ws[pA*16 + c16];
  int nbB = idx_ws[pB*16 + c16];

  // gather neighbor features for both points
  const float* frA = feats + (bbA*N_ + nbA)*128;
  const float* frB = feats + (bbB*N_ + nbB)*128;
  bf16x8 a1A[4], a1B[4];
  #pragma unroll
  for (int ks = 0; ks < 4; ++ks){
    f32x4 lo = *(const f32x4*)(frA + ks*32 + g*8);
    f32x4 hi = *(const f32x4*)(frA + ks*32 + g*8 + 4);
    bf16x8 v;
    v[0]=bfr(lo[0]); v[1]=bfr(lo[1]); v[2]=bfr(lo[2]); v[3]=bfr(lo[3]);
    v[4]=bfr(hi[0]); v[5]=bfr(hi[1]); v[6]=bfr(hi[2]); v[7]=bfr(hi[3]);
    a1A[ks] = v;
    lo = *(const f32x4*)(frB + ks*32 + g*8);
    hi = *(const f32x4*)(frB + ks*32 + g*8 + 4);
    v[0]=bfr(lo[0]); v[1]=bfr(lo[1]); v[2]=bfr(lo[2]); v[3]=bfr(lo[3]);
    v[4]=bfr(hi[0]); v[5]=bfr(hi[1]); v[6]=bfr(hi[2]); v[7]=bfr(hi[3]);
    a1B[ks] = v;
  }

  // GEMM1 with shared B fragments
  f32x4 accA[8], accB[8];
  #pragma unroll
  for (int t = 0; t < 8; ++t){ accA[t] = (f32x4){0.f,0.f,0.f,0.f}; accB[t] = (f32x4){0.f,0.f,0.f,0.f}; }
  #pragma unroll
  for (int t = 0; t < 8; ++t){
    #pragma unroll
    for (int ks = 0; ks < 4; ++ks){
      bf16x8 w = *(const bf16x8*)(W1T + (t*16 + c16)*128 + ks*32 + g*8);
      accA[t] = __builtin_amdgcn_mfma_f32_16x16x32_bf16(a1A[ks], w, accA[t], 0, 0, 0);
      accB[t] = __builtin_amdgcn_mfma_f32_16x16x32_bf16(a1B[ks], w, accB[t], 0, 0, 0);
    }
  }

  // LN1/geo params
  float p_b1[8], p_g1[8], p_e1[8], p_c2[8];
  #pragma unroll
  for (int t = 0; t < 8; ++t){
    int col = t*16 + c16;
    p_b1[t] = b1[col]; p_g1[t] = ln1g[col]; p_e1[t] = ln1b[col]; p_c2[t] = cb2[col];
  }

  short* fw = &fuse[wv][0][0];

  // ---- phase A: build concat(tf,geo) for point A, read a3A
  ln_silu_store(accA, p_b1, p_g1, p_e1, fw, g, c16);
  {
    const float* cx = xyz + (bbA*N_ + nAi)*3;
    const float* nx = xyz + (bbA*N_ + nbA)*3;
    geo_store(nx[0]-cx[0], nx[1]-cx[1], nx[2]-cx[2],
              s_cw1, s_cb1, s_sc, s_sh, cw2b, p_c2, fw, g, c16);
  }
  __syncthreads();
  bf16x8 a3A[8];
  #pragma unroll
  for (int ks = 0; ks < 8; ++ks)
    a3A[ks] = *(const bf16x8*)(fw + c16*264 + ks*32 + g*8);
  __syncthreads();

  // ---- phase B: rebuild buffer for point B, read a3B
  ln_silu_store(accB, p_b1, p_g1, p_e1, fw, g, c16);
  {
    const float* cx = xyz + (bbB*N_ + nBi)*3;
    const float* nx = xyz + (bbB*N_ + nbB)*3;
    geo_store(nx[0]-cx[0], nx[1]-cx[1], nx[2]-cx[2],
              s_cw1, s_cb1, s_sc, s_sh, cw2b, p_c2, fw, g, c16);
  }
  __syncthreads();
  bf16x8 a3B[8];
  #pragma unroll
  for (int ks = 0; ks < 8; ++ks)
    a3B[ks] = *(const bf16x8*)(fw + c16*264 + ks*32 + g*8);

  // GEMM3 with shared B fragments
  #pragma unroll
  for (int t = 0; t < 8; ++t){ accA[t] = (f32x4){0.f,0.f,0.f,0.f}; accB[t] = (f32x4){0.f,0.f,0.f,0.f}; }
  #pragma unroll
  for (int t = 0; t < 8; ++t){
    bf16x8 w[8];
    #pragma unroll
    for (int ks = 0; ks < 8; ++ks)
      w[ks] = *(const bf16x8*)(WfT + (t*16 + c16)*256 + ks*32 + g*8);
    #pragma unroll
    for (int ks = 0; ks < 8; ++ks){
      accA[t] = __builtin_amdgcn_mfma_f32_16x16x32_bf16(a3A[ks], w[ks], accA[t], 0, 0, 0);
      accB[t] = __builtin_amdgcn_mfma_f32_16x16x32_bf16(a3B[ks], w[ks], accB[t], 0, 0, 0);
    }
  }

  // epilogue params loaded late to cap register pressure
  float p_bf[8], p_gf[8], p_ef[8], p_al[8], p_bt[8];
  #pragma unroll
  for (int t = 0; t < 8; ++t){
    int col = t*16 + c16;
    p_bf[t] = bfb[col]; p_gf[t] = lnfg[col]; p_ef[t] = lnfb[col];
    p_al[t] = alpha[col]; p_bt[t] = beta[col];
  }
  epilogue_store(accA, p_bf, p_gf, p_ef, p_al, p_bt, pA, g, c16, out);
  epilogue_store(accB, p_bf, p_gf, p_ef, p_al, p_bt, pB, g, c16, out);
}

// ---------------- launch ----------------
extern "C" void kernel_launch(void* const* d_in, const int* in_sizes, int n_in,
                              void* d_out, int out_size, void* d_ws, size_t ws_size,
                              hipStream_t stream)
{
  (void)in_sizes; (void)n_in; (void)out_size; (void)ws_size;
  const float* xyz   = (const float*)d_in[0];
  const float* feats = (const float*)d_in[1];
  const float* W1    = (const float*)d_in[2];
  const float* b1    = (const float*)d_in[3];
  const float* ln1g  = (const float*)d_in[4];
  const float* ln1b  = (const float*)d_in[5];
  const float* cw1   = (const float*)d_in[6];
  const float* cb1   = (const float*)d_in[7];
  const float* bng   = (const float*)d_in[8];
  const float* bnb   = (const float*)d_in[9];
  const float* cw2   = (const float*)d_in[10];
  const float* cb2   = (const float*)d_in[11];
  const float* Wf    = (const float*)d_in[12];
  const float* bfb   = (const float*)d_in[13];
  const float* lnfg  = (const float*)d_in[14];
  const float* lnfb  = (const float*)d_in[15];
  const float* alpha = (const float*)d_in[16];
  const float* beta  = (const float*)d_in[17];

  char* ws = (char*)d_ws;
  int*   idx   = (int*)  (ws);                 // 32768*16*4 = 2,097,152 B
  float* stats = (float*)(ws + 2097152);       // 16 floats
  float* bnsc  = (float*)(ws + 2097216);       // 64 floats
  float* bnsh  = (float*)(ws + 2097472);       // 64 floats
  short* W1T   = (short*)(ws + 2097728);       // 32 KB
  short* WfT   = (short*)(ws + 2130496);       // 64 KB
  short* cw2b  = (short*)(ws + 2196032);       // 16 KB

  hipLaunchKernelGGL(prep_kernel, dim3(225), dim3(256), 0, stream,
                     W1, Wf, cw2, W1T, WfT, cw2b, stats);
  hipLaunchKernelGGL(knn_kernel, dim3(512), dim3(512), 0, stream,
                     xyz, idx, stats);
  hipLaunchKernelGGL(bn_finalize_kernel, dim3(1), dim3(64), 0, stream,
                     stats, cw1, cb1, bng, bnb, bnsc, bnsh);
  hipLaunchKernelGGL(lga_main_kernel, dim3(4096), dim3(256), 0, stream,
                     xyz, feats, idx, W1T, WfT, cw2b,
                     b1, ln1g, ln1b, cw1, cb1, bnsc, bnsh,
                     cb2, bfb, lnfg, lnfb, alpha, beta,
                     (float*)d_out);
  // diagnostic probe: reads idx, writes nothing; dur_us >1.5ms iff bitonic
  // selection mismatches the proven insert-based selection
  hipLaunchKernelGGL(knn_bitonic_probe, dim3(512), dim3(512), 0, stream,
                     xyz, idx);
}

// Round 12
// 2604.196 us; speedup vs baseline: 2.8335x; 2.8335x over previous
//
#include <hip/hip_runtime.h>
#include <hip/hip_bf16.h>

#define B_ 8
#define N_ 4096
#define K_ 16
#define D_ 128

typedef short bf16x8 __attribute__((ext_vector_type(8)));
typedef float f32x4 __attribute__((ext_vector_type(4)));
typedef unsigned long long u64;

__device__ __forceinline__ short bfr(float x){
  __hip_bfloat16 h = __float2bfloat16(x);
  return *reinterpret_cast<short*>(&h);
}

// ---------------- prep: bf16 transposed weights + zero stats ----------------
__global__ __launch_bounds__(256) void prep_kernel(
    const float* __restrict__ W1, const float* __restrict__ Wf, const float* __restrict__ cw2,
    short* __restrict__ W1T, short* __restrict__ WfT, short* __restrict__ cw2b,
    float* __restrict__ stats)
{
  int t = blockIdx.x*256 + threadIdx.x;
  if (t < 16384) {                       // W1T[d][c] = W1[c][d]
    int d = t >> 7, c = t & 127;
    W1T[t] = bfr(W1[c*128 + d]);
  } else if (t < 49152) {                // WfT[d][c] = Wf[c][d]
    int u = t - 16384;
    int d = u >> 8, c = u & 255;
    WfT[u] = bfr(Wf[c*128 + d]);
  } else if (t < 57344) {                // cw2 already [d][c] row-major
    int u = t - 49152;
    cw2b[u] = bfr(cw2[u]);
  } else if (t < 57360) {
    stats[t - 57344] = 0.0f;
  }
}

// ---------------- knn (R9 verbatim — proven green; DO NOT TOUCH) ----------------
__device__ __forceinline__ void insert16(float (&bd)[16], int (&bi)[16], float d, int cid){
  #pragma unroll
  for (int j = 15; j >= 1; --j){
    bool ltj = d < bd[j];
    bool ltp = d < bd[j-1];
    float nd = ltj ? (ltp ? bd[j-1] : d) : bd[j];
    int   ni = ltj ? (ltp ? bi[j-1] : cid) : bi[j];
    bd[j] = nd; bi[j] = ni;
  }
  bool lt0 = d < bd[0];
  bd[0] = lt0 ? d : bd[0];
  bi[0] = lt0 ? cid : bi[0];
}

__device__ __forceinline__ void insert16t(float (&bd)[16], int (&bi)[16], float d, int cid){
  bool lt[16];
  #pragma unroll
  for (int j = 0; j < 16; ++j)
    lt[j] = (d < bd[j]) || ((d == bd[j]) && (cid < bi[j]));
  #pragma unroll
  for (int j = 15; j >= 1; --j){
    float nd = lt[j] ? (lt[j-1] ? bd[j-1] : d) : bd[j];
    int   ni = lt[j] ? (lt[j-1] ? bi[j-1] : cid) : bi[j];
    bd[j] = nd; bi[j] = ni;
  }
  if (lt[0]){ bd[0] = d; bi[0] = cid; }
}

__global__ __launch_bounds__(512) void knn_kernel(
    const float* __restrict__ xyz, int* __restrict__ idx_out, float* __restrict__ stats)
{
  __shared__ float4 cand[N_];            // 64 KB: x,y,z,|p|^2 (XOR-swizzled)
  int b    = blockIdx.x >> 6;            // 64 blocks per batch
  int qblk = (blockIdx.x & 63) << 6;     // 64 queries per block
  const float* xb = xyz + b*N_*3;
  for (int i = threadIdx.x; i < N_; i += 512){
    float x = xb[i*3+0], y = xb[i*3+1], z = xb[i*3+2];
    int e = i ^ ((i >> 9) & 7);          // swizzled slot (bijection within slice)
    cand[e] = make_float4(x, y, z, x*x + y*y + z*z);
  }
  __syncthreads();

  int wv = threadIdx.x >> 6, lane = threadIdx.x & 63;
  int q = lane & 7;                      // query within wave's 8
  int s = lane >> 3;                     // slice 0..7
  int qi = qblk + (wv << 3) + q;         // batch-local query index
  float4 qc = cand[qi ^ ((qi >> 9) & 7)];

  float bd[16]; int bi[16];
  #pragma unroll
  for (int j = 0; j < 16; ++j){ bd[j] = 3.4e38f; bi[j] = 0x7fffffff; }

  int cbase = s << 9;
  float4 cb0[4], cb1[4];
  #pragma unroll
  for (int j = 0; j < 4; ++j) cb0[j] = cand[cbase + (j ^ s)];
  for (int m = 0; m < 512; m += 4){
    int mn = (m + 4) & 511;
    #pragma unroll
    for (int j = 0; j < 4; ++j) cb1[j] = cand[cbase + ((mn + j) ^ s)];
    #pragma unroll
    for (int j = 0; j < 4; ++j){
      float4 c = cb0[j];
      float t = qc.x*c.x + qc.y*c.y + qc.z*c.z;
      float d = (qc.w + c.w) - 2.0f*t;
      if (d < bd[15]) insert16(bd, bi, d, cbase + m + j);
    }
    #pragma unroll
    for (int j = 0; j < 4; ++j) cb0[j] = cb1[j];
  }

  #pragma unroll
  for (int xm = 32; xm >= 8; xm >>= 1){
    bool absorb = (lane & xm) == 0;
    #pragma unroll
    for (int j = 0; j < 16; ++j){
      float pdj = __shfl_xor(bd[j], xm);
      int   pij = __shfl_xor(bi[j], xm);
      if (absorb) insert16t(bd, bi, pdj, pij);
    }
  }

  float sv[9];
  #pragma unroll
  for (int i = 0; i < 9; ++i) sv[i] = 0.0f;
  if (s == 0){
    int gq = b*N_ + qi;
    #pragma unroll
    for (int j = 0; j < 16; ++j){
      idx_out[gq*16 + j] = bi[j];
      int be = bi[j] ^ ((bi[j] >> 9) & 7);
      float4 c = cand[be];
      float rx = c.x - qc.x, ry = c.y - qc.y, rz = c.z - qc.z;
      sv[0] += rx;    sv[1] += ry;    sv[2] += rz;
      sv[3] += rx*rx; sv[4] += ry*ry; sv[5] += rz*rz;
      sv[6] += rx*ry; sv[7] += rx*rz; sv[8] += ry*rz;
    }
  }
  #pragma unroll
  for (int i = 0; i < 9; ++i){
    float v = sv[i];
    #pragma unroll
    for (int mask = 1; mask < 64; mask <<= 1) v += __shfl_xor(v, mask);
    if (lane == 0) atomicAdd(&stats[i], v);
  }
}

// ---------------- two-phase knn probe (diagnostic: WRITES NOTHING) ----------
__device__ __forceinline__ u64 pack_key(float d, int idx){
  unsigned ub = __float_as_uint(d);
  ub ^= (unsigned)(((int)ub >> 31) | 0x80000000);
  return ((u64)ub << 32) | (unsigned)idx;
}
__device__ __forceinline__ void ce_asc(u64 &a, u64 &b){
  u64 lo = a < b ? a : b;
  u64 hi = a < b ? b : a;
  a = lo; b = hi;
}
__device__ __forceinline__ void merge16(u64 (&bd)[16], const u64 (&c)[16]){
  u64 m[16];
  #pragma unroll
  for (int i = 0; i < 16; ++i)
    m[i] = bd[i] < c[15-i] ? bd[i] : c[15-i];
  #pragma unroll
  for (int j = 8; j > 0; j >>= 1){
    #pragma unroll
    for (int i = 0; i < 16; ++i){
      int l = i ^ j;
      if (l > i) ce_asc(m[i], m[l]);
    }
  }
  #pragma unroll
  for (int i = 0; i < 16; ++i) bd[i] = m[i];
}
__device__ __forceinline__ void cef(float &a, float &b){
  float lo = fminf(a, b);
  float hi = fmaxf(a, b);
  a = lo; b = hi;
}
__device__ __forceinline__ void sort16f(float (&k)[16]){
  #pragma unroll
  for (int kk = 2; kk <= 16; kk <<= 1){
    #pragma unroll
    for (int j = kk >> 1; j > 0; j >>= 1){
      #pragma unroll
      for (int i = 0; i < 16; ++i){
        int l = i ^ j;
        if (l > i){
          if ((i & kk) == 0) cef(k[i], k[l]);
          else               cef(k[l], k[i]);
        }
      }
    }
  }
}
__device__ __forceinline__ void merge16f(float (&bd)[16], const float (&c)[16]){
  float m[16];
  #pragma unroll
  for (int i = 0; i < 16; ++i) m[i] = fminf(bd[i], c[15-i]);
  #pragma unroll
  for (int j = 8; j > 0; j >>= 1){
    #pragma unroll
    for (int i = 0; i < 16; ++i){
      int l = i ^ j;
      if (l > i) cef(m[i], m[l]);
    }
  }
  #pragma unroll
  for (int i = 0; i < 16; ++i) bd[i] = m[i];
}
__device__ __forceinline__ void insert12u(u64 (&kb)[12], u64 key){
  bool lt[12];
  #pragma unroll
  for (int j = 0; j < 12; ++j) lt[j] = key < kb[j];
  #pragma unroll
  for (int j = 11; j >= 1; --j)
    kb[j] = lt[j] ? (lt[j-1] ? kb[j-1] : key) : kb[j];
  if (lt[0]) kb[0] = key;
}

// Phase A: exact per-query 16th-smallest d via index-free f32 bitonic networks.
// Phase B: rescan with slack gate, collect lex-exact (d,idx), merge, compare.
// Mismatch -> mc*50K dependent-FMA spin -> probe dur visibly inflated.
__global__ __launch_bounds__(512) void knn2p_probe(
    const float* __restrict__ xyz, const int* __restrict__ idx_ref)
{
  __shared__ float4 cand[N_];
  int b    = blockIdx.x >> 6;
  int qblk = (blockIdx.x & 63) << 6;
  const float* xb = xyz + b*N_*3;
  for (int i = threadIdx.x; i < N_; i += 512){
    float x = xb[i*3+0], y = xb[i*3+1], z = xb[i*3+2];
    int e = i ^ ((i >> 9) & 7);
    cand[e] = make_float4(x, y, z, x*x + y*y + z*z);
  }
  __syncthreads();

  int lane = threadIdx.x & 63;
  int q = lane & 7;
  int s = lane >> 3;
  int qi = qblk + ((threadIdx.x >> 6) << 3) + q;
  float4 qc = cand[qi ^ ((qi >> 9) & 7)];
  int cbase = s << 9;

  // phase A
  float ad[16];
  #pragma unroll
  for (int j = 0; j < 16; ++j) ad[j] = 3.4e38f;
  for (int m = 0; m < 512; m += 16){
    float ck[16];
    #pragma unroll
    for (int j = 0; j < 16; ++j){
      float4 c = cand[cbase + ((m + j) ^ s)];
      float t = qc.x*c.x + qc.y*c.y + qc.z*c.z;
      ck[j] = (qc.w + c.w) - 2.0f*t;
    }
    sort16f(ck);
    merge16f(ad, ck);
  }
  #pragma unroll
  for (int xm = 8; xm <= 32; xm <<= 1){
    float pc[16];
    #pragma unroll
    for (int j = 0; j < 16; ++j) pc[j] = __shfl_xor(ad[j], xm);
    merge16f(ad, pc);
  }
  float gate = ad[15] * 1.0000005f + 1e-6f;   // few-ulp slack for A/B drift

  // phase B
  u64 kb[12];
  #pragma unroll
  for (int j = 0; j < 12; ++j) kb[j] = 0xFFFFFFFFFFFFFFFFull;
  for (int m = 0; m < 512; ++m){
    float4 c = cand[cbase + (m ^ s)];
    float t = qc.x*c.x + qc.y*c.y + qc.z*c.z;
    float d = (qc.w + c.w) - 2.0f*t;
    if (d <= gate) insert12u(kb, pack_key(d, cbase + m));
  }
  u64 bd[16];
  #pragma unroll
  for (int j = 0; j < 16; ++j) bd[j] = (j < 12) ? kb[j] : 0xFFFFFFFFFFFFFFFFull;
  #pragma unroll
  for (int xm = 8; xm <= 32; xm <<= 1){
    u64 pc[16];
    #pragma unroll
    for (int j = 0; j < 16; ++j){
      unsigned lo = __shfl_xor((unsigned)(bd[j] & 0xFFFFFFFFu), xm);
      unsigned hi = __shfl_xor((unsigned)(bd[j] >> 32), xm);
      pc[j] = ((u64)hi << 32) | lo;
    }
    merge16(bd, pc);
  }

  int mc = 0;
  if (s == 0){
    int gq = b*N_ + qi;
    #pragma unroll
    for (int j = 0; j < 16; ++j)
      mc += (idx_ref[gq*16 + j] != (int)(bd[j] & 0xFFFFFFFFu)) ? 1 : 0;
  }
  #pragma unroll
  for (int mask = 1; mask < 64; mask <<= 1) mc += __shfl_xor(mc, mask);
  int spin = (mc > 8 ? 8 : mc) * 50000;
  float accv = 1.0f;
  for (int i = 0; i < spin; ++i) accv = accv*1.0000001f + 1e-7f;
  asm volatile("" :: "v"(accv));
}

// ---------------- BN finalize ----------------
__global__ void bn_finalize_kernel(
    const float* __restrict__ stats, const float* __restrict__ cw1, const float* __restrict__ cb1,
    const float* __restrict__ bn_g, const float* __restrict__ bn_b,
    float* __restrict__ bnsc, float* __restrict__ bnsh)
{
  int o = threadIdx.x;
  if (o >= 64) return;
  const float inv = 1.0f / (float)(B_*N_*K_);
  float m1x = stats[0]*inv, m1y = stats[1]*inv, m1z = stats[2]*inv;
  float mxx = stats[3]*inv, myy = stats[4]*inv, mzz = stats[5]*inv;
  float mxy = stats[6]*inv, mxz = stats[7]*inv, myz = stats[8]*inv;
  float w0 = cw1[o*3], w1 = cw1[o*3+1], w2 = cw1[o*3+2], cb = cb1[o];
  float wm = w0*m1x + w1*m1y + w2*m1z;
  float mu = wm + cb;
  float e2 = w0*w0*mxx + w1*w1*myy + w2*w2*mzz
           + 2.0f*(w0*w1*mxy + w0*w2*mxz + w1*w2*myz)
           + 2.0f*cb*wm + cb*cb;
  float var = e2 - mu*mu;
  float sc = bn_g[o] * rsqrtf(var + 1e-5f);
  bnsc[o] = sc;
  bnsh[o] = bn_b[o] - mu*sc;
}

// ---------------- main fused kernel: 1 wave = 2 points (shared B-frags) -----
__device__ __forceinline__ void ln_silu_store(
    f32x4 (&acc)[8], const float (&pb)[8], const float (&pg)[8], const float (&pe)[8],
    short* fw, int g, int c16)
{
  float sm[4] = {0,0,0,0}, sq[4] = {0,0,0,0};
  #pragma unroll
  for (int t = 0; t < 8; ++t){
    #pragma unroll
    for (int r = 0; r < 4; ++r){
      float v = acc[t][r] + pb[t];
      acc[t][r] = v;
      sm[r] += v; sq[r] += v*v;
    }
  }
  #pragma unroll
  for (int mask = 1; mask < 16; mask <<= 1){
    #pragma unroll
    for (int r = 0; r < 4; ++r){ sm[r] += __shfl_xor(sm[r], mask); sq[r] += __shfl_xor(sq[r], mask); }
  }
  #pragma unroll
  for (int r = 0; r < 4; ++r){
    float mean = sm[r] * (1.0f/128.0f);
    float var  = sq[r]*(1.0f/128.0f) - mean*mean;
    float rstd = rsqrtf(var + 1e-5f);
    #pragma unroll
    for (int t = 0; t < 8; ++t){
      float y = (acc[t][r] - mean) * rstd * pg[t] + pe[t];
      y = y / (1.0f + __expf(-y));       // SiLU
      fw[(g*4 + r)*264 + t*16 + c16] = bfr(y);
    }
  }
}

__device__ __forceinline__ void geo_store(
    float rx, float ry, float rz,
    const float* s_cw1, const float* s_cb1, const float* s_sc, const float* s_sh,
    const short* __restrict__ cw2b, const float (&pc2)[8],
    short* fw, int g, int c16)
{
  bf16x8 a2[2];
  #pragma unroll
  for (int ks = 0; ks < 2; ++ks){
    bf16x8 v;
    #pragma unroll
    for (int j = 0; j < 8; ++j){
      int o = ks*32 + g*8 + j;
      float h = s_cw1[o*3]*rx + s_cw1[o*3+1]*ry + s_cw1[o*3+2]*rz + s_cb1[o];
      h = h * s_sc[o] + s_sh[o];
      h = h / (1.0f + __expf(-h));
      v[j] = bfr(h);
    }
    a2[ks] = v;
  }
  #pragma unroll
  for (int t = 0; t < 8; ++t){
    f32x4 a = (f32x4){0.f,0.f,0.f,0.f};
    #pragma unroll
    for (int ks = 0; ks < 2; ++ks){
      bf16x8 w = *(const bf16x8*)(cw2b + (t*16 + c16)*64 + ks*32 + g*8);
      a = __builtin_amdgcn_mfma_f32_16x16x32_bf16(a2[ks], w, a, 0, 0, 0);
    }
    #pragma unroll
    for (int r = 0; r < 4; ++r)
      fw[(g*4 + r)*264 + 128 + t*16 + c16] = bfr(a[r] + pc2[t]);
  }
}

__device__ __forceinline__ void epilogue_store(
    f32x4 (&acc)[8], const float (&pbf)[8], const float (&pgf)[8], const float (&pef)[8],
    const float (&pal)[8], const float (&pbt)[8],
    int point, int g, int c16, float* __restrict__ out)
{
  float sm[4] = {0,0,0,0}, sq[4] = {0,0,0,0};
  #pragma unroll
  for (int t = 0; t < 8; ++t){
    #pragma unroll
    for (int r = 0; r < 4; ++r){
      float v = acc[t][r] + pbf[t];
      acc[t][r] = v;
      sm[r] += v; sq[r] += v*v;
    }
  }
  #pragma unroll
  for (int mask = 1; mask < 16; mask <<= 1){
    #pragma unroll
    for (int r = 0; r < 4; ++r){ sm[r] += __shfl_xor(sm[r], mask); sq[r] += __shfl_xor(sq[r], mask); }
  }
  #pragma unroll
  for (int r = 0; r < 4; ++r){
    float mean = sm[r] * (1.0f/128.0f);
    float var  = sq[r]*(1.0f/128.0f) - mean*mean;
    float rstd = rsqrtf(var + 1e-5f);
    #pragma unroll
    for (int t = 0; t < 8; ++t){
      float y = (acc[t][r] - mean) * rstd * pgf[t] + pef[t];
      y = y / (1.0f + __expf(-y));
      acc[t][r] = pal[t]*y + pbt[t];
    }
  }
  float sr[4] = {0,0,0,0};
  #pragma unroll
  for (int t = 0; t < 8; ++t){
    #pragma unroll
    for (int r = 0; r < 4; ++r) sr[r] += acc[t][r];
  }
  #pragma unroll
  for (int mask = 1; mask < 16; mask <<= 1){
    #pragma unroll
    for (int r = 0; r < 4; ++r) sr[r] += __shfl_xor(sr[r], mask);
  }
  float mx = fmaxf(fmaxf(sr[0], sr[1]), fmaxf(sr[2], sr[3]));
  mx = fmaxf(mx, __shfl_xor(mx, 16));
  mx = fmaxf(mx, __shfl_xor(mx, 32));
  float e[4]; float se = 0.f;
  #pragma unroll
  for (int r = 0; r < 4; ++r){ e[r] = __expf(sr[r] - mx); se += e[r]; }
  se += __shfl_xor(se, 16);
  se += __shfl_xor(se, 32);
  float inv = 1.0f / se;
  #pragma unroll
  for (int r = 0; r < 4; ++r) e[r] *= inv;
  #pragma unroll
  for (int t = 0; t < 8; ++t){
    float o = e[0]*acc[t][0] + e[1]*acc[t][1] + e[2]*acc[t][2] + e[3]*acc[t][3];
    o += __shfl_xor(o, 16);
    o += __shfl_xor(o, 32);
    if (g == 0) out[point*128 + t*16 + c16] = o;
  }
}

__global__ __launch_bounds__(256) void lga_main_kernel(
    const float* __restrict__ xyz, const float* __restrict__ feats, const int* __restrict__ idx_ws,
    const short* __restrict__ W1T, const short* __restrict__ WfT, const short* __restrict__ cw2b,
    const float* __restrict__ b1, const float* __restrict__ ln1g, const float* __restrict__ ln1b,
    const float* __restrict__ cw1, const float* __restrict__ cb1,
    const float* __restrict__ bnsc, const float* __restrict__ bnsh,
    const float* __restrict__ cb2, const float* __restrict__ bfb,
    const float* __restrict__ lnfg, const float* __restrict__ lnfb,
    const float* __restrict__ alpha, const float* __restrict__ beta,
    float* __restrict__ out)
{
  __shared__ short fuse[4][16][264];     // per-wave buffer, time-shared by the 2 points
  __shared__ float s_cw1[192], s_cb1[64], s_sc[64], s_sh[64];

  int tid = threadIdx.x;
  for (int i = tid; i < 192; i += 256) s_cw1[i] = cw1[i];
  if (tid < 64){ s_cb1[tid] = cb1[tid]; s_sc[tid] = bnsc[tid]; s_sh[tid] = bnsh[tid]; }
  __syncthreads();

  int wv = tid >> 6, lane = tid & 63, g = lane >> 4, c16 = lane & 15;
  int pA = blockIdx.x*8 + wv*2;
  int pB = pA + 1;
  int bbA = pA >> 12, nAi = pA & 4095;
  int bbB = pB >> 12, nBi = pB & 4095;

  int nbA = idx_ws[pA*16 + c16];
  int nbB = idx_ws[pB*16 + c16];

  // gather neighbor features for both points
  const float* frA = feats + (bbA*N_ + nbA)*128;
  const float* frB = feats + (bbB*N_ + nbB)*128;
  bf16x8 a1A[4], a1B[4];
  #pragma unroll
  for (int ks = 0; ks < 4; ++ks){
    f32x4 lo = *(const f32x4*)(frA + ks*32 + g*8);
    f32x4 hi = *(const f32x4*)(frA + ks*32 + g*8 + 4);
    bf16x8 v;
    v[0]=bfr(lo[0]); v[1]=bfr(lo[1]); v[2]=bfr(lo[2]); v[3]=bfr(lo[3]);
    v[4]=bfr(hi[0]); v[5]=bfr(hi[1]); v[6]=bfr(hi[2]); v[7]=bfr(hi[3]);
    a1A[ks] = v;
    lo = *(const f32x4*)(frB + ks*32 + g*8);
    hi = *(const f32x4*)(frB + ks*32 + g*8 + 4);
    v[0]=bfr(lo[0]); v[1]=bfr(lo[1]); v[2]=bfr(lo[2]); v[3]=bfr(lo[3]);
    v[4]=bfr(hi[0]); v[5]=bfr(hi[1]); v[6]=bfr(hi[2]); v[7]=bfr(hi[3]);
    a1B[ks] = v;
  }

  // GEMM1 with shared B fragments
  f32x4 accA[8], accB[8];
  #pragma unroll
  for (int t = 0; t < 8; ++t){ accA[t] = (f32x4){0.f,0.f,0.f,0.f}; accB[t] = (f32x4){0.f,0.f,0.f,0.f}; }
  #pragma unroll
  for (int t = 0; t < 8; ++t){
    #pragma unroll
    for (int ks = 0; ks < 4; ++ks){
      bf16x8 w = *(const bf16x8*)(W1T + (t*16 + c16)*128 + ks*32 + g*8);
      accA[t] = __builtin_amdgcn_mfma_f32_16x16x32_bf16(a1A[ks], w, accA[t], 0, 0, 0);
      accB[t] = __builtin_amdgcn_mfma_f32_16x16x32_bf16(a1B[ks], w, accB[t], 0, 0, 0);
    }
  }

  // LN1/geo params
  float p_b1[8], p_g1[8], p_e1[8], p_c2[8];
  #pragma unroll
  for (int t = 0; t < 8; ++t){
    int col = t*16 + c16;
    p_b1[t] = b1[col]; p_g1[t] = ln1g[col]; p_e1[t] = ln1b[col]; p_c2[t] = cb2[col];
  }

  short* fw = &fuse[wv][0][0];

  // ---- phase A: build concat(tf,geo) for point A, read a3A
  ln_silu_store(accA, p_b1, p_g1, p_e1, fw, g, c16);
  {
    const float* cx = xyz + (bbA*N_ + nAi)*3;
    const float* nx = xyz + (bbA*N_ + nbA)*3;
    geo_store(nx[0]-cx[0], nx[1]-cx[1], nx[2]-cx[2],
              s_cw1, s_cb1, s_sc, s_sh, cw2b, p_c2, fw, g, c16);
  }
  __syncthreads();
  bf16x8 a3A[8];
  #pragma unroll
  for (int ks = 0; ks < 8; ++ks)
    a3A[ks] = *(const bf16x8*)(fw + c16*264 + ks*32 + g*8);
  __syncthreads();

  // ---- phase B: rebuild buffer for point B, read a3B
  ln_silu_store(accB, p_b1, p_g1, p_e1, fw, g, c16);
  {
    const float* cx = xyz + (bbB*N_ + nBi)*3;
    const float* nx = xyz + (bbB*N_ + nbB)*3;
    geo_store(nx[0]-cx[0], nx[1]-cx[1], nx[2]-cx[2],
              s_cw1, s_cb1, s_sc, s_sh, cw2b, p_c2, fw, g, c16);
  }
  __syncthreads();
  bf16x8 a3B[8];
  #pragma unroll
  for (int ks = 0; ks < 8; ++ks)
    a3B[ks] = *(const bf16x8*)(fw + c16*264 + ks*32 + g*8);

  // GEMM3 with shared B fragments
  #pragma unroll
  for (int t = 0; t < 8; ++t){ accA[t] = (f32x4){0.f,0.f,0.f,0.f}; accB[t] = (f32x4){0.f,0.f,0.f,0.f}; }
  #pragma unroll
  for (int t = 0; t < 8; ++t){
    bf16x8 w[8];
    #pragma unroll
    for (int ks = 0; ks < 8; ++ks)
      w[ks] = *(const bf16x8*)(WfT + (t*16 + c16)*256 + ks*32 + g*8);
    #pragma unroll
    for (int ks = 0; ks < 8; ++ks){
      accA[t] = __builtin_amdgcn_mfma_f32_16x16x32_bf16(a3A[ks], w[ks], accA[t], 0, 0, 0);
      accB[t] = __builtin_amdgcn_mfma_f32_16x16x32_bf16(a3B[ks], w[ks], accB[t], 0, 0, 0);
    }
  }

  // epilogue params loaded late to cap register pressure
  float p_bf[8], p_gf[8], p_ef[8], p_al[8], p_bt[8];
  #pragma unroll
  for (int t = 0; t < 8; ++t){
    int col = t*16 + c16;
    p_bf[t] = bfb[col]; p_gf[t] = lnfg[col]; p_ef[t] = lnfb[col];
    p_al[t] = alpha[col]; p_bt[t] = beta[col];
  }
  epilogue_store(accA, p_bf, p_gf, p_ef, p_al, p_bt, pA, g, c16, out);
  epilogue_store(accB, p_bf, p_gf, p_ef, p_al, p_bt, pB, g, c16, out);
}

// ---------------- launch ----------------
extern "C" void kernel_launch(void* const* d_in, const int* in_sizes, int n_in,
                              void* d_out, int out_size, void* d_ws, size_t ws_size,
                              hipStream_t stream)
{
  (void)in_sizes; (void)n_in; (void)out_size; (void)ws_size;
  const float* xyz   = (const float*)d_in[0];
  const float* feats = (const float*)d_in[1];
  const float* W1    = (const float*)d_in[2];
  const float* b1    = (const float*)d_in[3];
  const float* ln1g  = (const float*)d_in[4];
  const float* ln1b  = (const float*)d_in[5];
  const float* cw1   = (const float*)d_in[6];
  const float* cb1   = (const float*)d_in[7];
  const float* bng   = (const float*)d_in[8];
  const float* bnb   = (const float*)d_in[9];
  const float* cw2   = (const float*)d_in[10];
  const float* cb2   = (const float*)d_in[11];
  const float* Wf    = (const float*)d_in[12];
  const float* bfb   = (const float*)d_in[13];
  const float* lnfg  = (const float*)d_in[14];
  const float* lnfb  = (const float*)d_in[15];
  const float* alpha = (const float*)d_in[16];
  const float* beta  = (const float*)d_in[17];

  char* ws = (char*)d_ws;
  int*   idx   = (int*)  (ws);                 // 32768*16*4 = 2,097,152 B
  float* stats = (float*)(ws + 2097152);       // 16 floats
  float* bnsc  = (float*)(ws + 2097216);       // 64 floats
  float* bnsh  = (float*)(ws + 2097472);       // 64 floats
  short* W1T   = (short*)(ws + 2097728);       // 32 KB
  short* WfT   = (short*)(ws + 2130496);       // 64 KB
  short* cw2b  = (short*)(ws + 2196032);       // 16 KB

  hipLaunchKernelGGL(prep_kernel, dim3(225), dim3(256), 0, stream,
                     W1, Wf, cw2, W1T, WfT, cw2b, stats);
  hipLaunchKernelGGL(knn_kernel, dim3(512), dim3(512), 0, stream,
                     xyz, idx, stats);
  hipLaunchKernelGGL(bn_finalize_kernel, dim3(1), dim3(64), 0, stream,
                     stats, cw1, cb1, bng, bnb, bnsc, bnsh);
  hipLaunchKernelGGL(lga_main_kernel, dim3(4096), dim3(256), 0, stream,
                     xyz, feats, idx, W1T, WfT, cw2b,
                     b1, ln1g, ln1b, cw1, cb1, bnsc, bnsh,
                     cb2, bfb, lnfg, lnfb, alpha, beta,
                     (float*)d_out);
  // diagnostic probe: reads idx, writes nothing; dur inflated iff two-phase
  // selection mismatches the proven insert-based selection
  hipLaunchKernelGGL(knn2p_probe, dim3(512), dim3(512), 0, stream,
                     xyz, idx);
}

// Round 13
// 1124.700 us; speedup vs baseline: 6.5609x; 2.3155x over previous
//
#include <hip/hip_runtime.h>
#include <hip/hip_bf16.h>

#define B_ 8
#define N_ 4096
#define K_ 16
#define D_ 128

typedef short bf16x8 __attribute__((ext_vector_type(8)));
typedef float f32x4 __attribute__((ext_vector_type(4)));

__device__ __forceinline__ short bfr(float x){
  __hip_bfloat16 h = __float2bfloat16(x);
  return *reinterpret_cast<short*>(&h);
}

// ---------------- prep: bf16 transposed weights + zero stats ----------------
__global__ __launch_bounds__(256) void prep_kernel(
    const float* __restrict__ W1, const float* __restrict__ Wf, const float* __restrict__ cw2,
    short* __restrict__ W1T, short* __restrict__ WfT, short* __restrict__ cw2b,
    float* __restrict__ stats)
{
  int t = blockIdx.x*256 + threadIdx.x;
  if (t < 16384) {                       // W1T[d][c] = W1[c][d]
    int d = t >> 7, c = t & 127;
    W1T[t] = bfr(W1[c*128 + d]);
  } else if (t < 49152) {                // WfT[d][c] = Wf[c][d]
    int u = t - 16384;
    int d = u >> 8, c = u & 255;
    WfT[u] = bfr(Wf[c*128 + d]);
  } else if (t < 57344) {                // cw2 already [d][c] row-major
    int u = t - 49152;
    cw2b[u] = bfr(cw2[u]);
  } else if (t < 57360) {
    stats[t - 57344] = 0.0f;
  }
}

// ---------------- knn (per-lane path R9-verbatim; block geometry 1024thr) ---
__device__ __forceinline__ void insert16(float (&bd)[16], int (&bi)[16], float d, int cid){
  #pragma unroll
  for (int j = 15; j >= 1; --j){
    bool ltj = d < bd[j];
    bool ltp = d < bd[j-1];
    float nd = ltj ? (ltp ? bd[j-1] : d) : bd[j];
    int   ni = ltj ? (ltp ? bi[j-1] : cid) : bi[j];
    bd[j] = nd; bi[j] = ni;
  }
  bool lt0 = d < bd[0];
  bd[0] = lt0 ? d : bd[0];
  bi[0] = lt0 ? cid : bi[0];
}

__device__ __forceinline__ void insert16t(float (&bd)[16], int (&bi)[16], float d, int cid){
  bool lt[16];
  #pragma unroll
  for (int j = 0; j < 16; ++j)
    lt[j] = (d < bd[j]) || ((d == bd[j]) && (cid < bi[j]));
  #pragma unroll
  for (int j = 15; j >= 1; --j){
    float nd = lt[j] ? (lt[j-1] ? bd[j-1] : d) : bd[j];
    int   ni = lt[j] ? (lt[j-1] ? bi[j-1] : cid) : bi[j];
    bd[j] = nd; bi[j] = ni;
  }
  if (lt[0]){ bd[0] = d; bi[0] = cid; }
}

// 1024 threads = 16 waves; 128 queries/block; 64KB cand buffer -> 2 blocks/CU
// = 32 waves/CU = 8 waves/SIMD (2x R9's occupancy; VGPR 56 fits 8 waves).
// Per-lane scan/merge code is byte-identical to the proven R9 kernel.
__global__ __launch_bounds__(1024) void knn_kernel(
    const float* __restrict__ xyz, int* __restrict__ idx_out, float* __restrict__ stats)
{
  __shared__ float4 cand[N_];            // 64 KB: x,y,z,|p|^2 (XOR-swizzled)
  int b    = blockIdx.x >> 5;            // 32 blocks per batch
  int qblk = (blockIdx.x & 31) << 7;     // 128 queries per block
  const float* xb = xyz + b*N_*3;
  for (int i = threadIdx.x; i < N_; i += 1024){
    float x = xb[i*3+0], y = xb[i*3+1], z = xb[i*3+2];
    int e = i ^ ((i >> 9) & 7);          // swizzled slot (bijection within slice)
    cand[e] = make_float4(x, y, z, x*x + y*y + z*z);
  }
  __syncthreads();

  int wv = threadIdx.x >> 6, lane = threadIdx.x & 63;
  int q = lane & 7;                      // query within wave's 8
  int s = lane >> 3;                     // slice 0..7
  int qi = qblk + (wv << 3) + q;         // batch-local query index
  float4 qc = cand[qi ^ ((qi >> 9) & 7)];

  float bd[16]; int bi[16];
  #pragma unroll
  for (int j = 0; j < 16; ++j){ bd[j] = 3.4e38f; bi[j] = 0x7fffffff; }

  int cbase = s << 9;
  float4 cb0[4], cb1[4];
  #pragma unroll
  for (int j = 0; j < 4; ++j) cb0[j] = cand[cbase + (j ^ s)];
  for (int m = 0; m < 512; m += 4){
    int mn = (m + 4) & 511;
    #pragma unroll
    for (int j = 0; j < 4; ++j) cb1[j] = cand[cbase + ((mn + j) ^ s)];
    #pragma unroll
    for (int j = 0; j < 4; ++j){
      float4 c = cb0[j];
      float t = qc.x*c.x + qc.y*c.y + qc.z*c.z;
      float d = (qc.w + c.w) - 2.0f*t;
      if (d < bd[15]) insert16(bd, bi, d, cbase + m + j);
    }
    #pragma unroll
    for (int j = 0; j < 4; ++j) cb0[j] = cb1[j];
  }

  #pragma unroll
  for (int xm = 32; xm >= 8; xm >>= 1){
    bool absorb = (lane & xm) == 0;
    #pragma unroll
    for (int j = 0; j < 16; ++j){
      float pdj = __shfl_xor(bd[j], xm);
      int   pij = __shfl_xor(bi[j], xm);
      if (absorb) insert16t(bd, bi, pdj, pij);
    }
  }

  float sv[9];
  #pragma unroll
  for (int i = 0; i < 9; ++i) sv[i] = 0.0f;
  if (s == 0){
    int gq = b*N_ + qi;
    #pragma unroll
    for (int j = 0; j < 16; ++j){
      idx_out[gq*16 + j] = bi[j];
      int be = bi[j] ^ ((bi[j] >> 9) & 7);
      float4 c = cand[be];
      float rx = c.x - qc.x, ry = c.y - qc.y, rz = c.z - qc.z;
      sv[0] += rx;    sv[1] += ry;    sv[2] += rz;
      sv[3] += rx*rx; sv[4] += ry*ry; sv[5] += rz*rz;
      sv[6] += rx*ry; sv[7] += rx*rz; sv[8] += ry*rz;
    }
  }
  #pragma unroll
  for (int i = 0; i < 9; ++i){
    float v = sv[i];
    #pragma unroll
    for (int mask = 1; mask < 64; mask <<= 1) v += __shfl_xor(v, mask);
    if (lane == 0) atomicAdd(&stats[i], v);
  }
}

// ---------------- BN finalize ----------------
__global__ void bn_finalize_kernel(
    const float* __restrict__ stats, const float* __restrict__ cw1, const float* __restrict__ cb1,
    const float* __restrict__ bn_g, const float* __restrict__ bn_b,
    float* __restrict__ bnsc, float* __restrict__ bnsh)
{
  int o = threadIdx.x;
  if (o >= 64) return;
  const float inv = 1.0f / (float)(B_*N_*K_);
  float m1x = stats[0]*inv, m1y = stats[1]*inv, m1z = stats[2]*inv;
  float mxx = stats[3]*inv, myy = stats[4]*inv, mzz = stats[5]*inv;
  float mxy = stats[6]*inv, mxz = stats[7]*inv, myz = stats[8]*inv;
  float w0 = cw1[o*3], w1 = cw1[o*3+1], w2 = cw1[o*3+2], cb = cb1[o];
  float wm = w0*m1x + w1*m1y + w2*m1z;
  float mu = wm + cb;
  float e2 = w0*w0*mxx + w1*w1*myy + w2*w2*mzz
           + 2.0f*(w0*w1*mxy + w0*w2*mxz + w1*w2*myz)
           + 2.0f*cb*wm + cb*cb;
  float var = e2 - mu*mu;
  float sc = bn_g[o] * rsqrtf(var + 1e-5f);
  bnsc[o] = sc;
  bnsh[o] = bn_b[o] - mu*sc;
}

// ---------------- main fused kernel: 1 wave = 2 points (shared B-frags) -----
__device__ __forceinline__ void ln_silu_store(
    f32x4 (&acc)[8], const float (&pb)[8], const float (&pg)[8], const float (&pe)[8],
    short* fw, int g, int c16)
{
  float sm[4] = {0,0,0,0}, sq[4] = {0,0,0,0};
  #pragma unroll
  for (int t = 0; t < 8; ++t){
    #pragma unroll
    for (int r = 0; r < 4; ++r){
      float v = acc[t][r] + pb[t];
      acc[t][r] = v;
      sm[r] += v; sq[r] += v*v;
    }
  }
  #pragma unroll
  for (int mask = 1; mask < 16; mask <<= 1){
    #pragma unroll
    for (int r = 0; r < 4; ++r){ sm[r] += __shfl_xor(sm[r], mask); sq[r] += __shfl_xor(sq[r], mask); }
  }
  #pragma unroll
  for (int r = 0; r < 4; ++r){
    float mean = sm[r] * (1.0f/128.0f);
    float var  = sq[r]*(1.0f/128.0f) - mean*mean;
    float rstd = rsqrtf(var + 1e-5f);
    #pragma unroll
    for (int t = 0; t < 8; ++t){
      float y = (acc[t][r] - mean) * rstd * pg[t] + pe[t];
      y = y / (1.0f + __expf(-y));       // SiLU
      fw[(g*4 + r)*264 + t*16 + c16] = bfr(y);
    }
  }
}

__device__ __forceinline__ void geo_store(
    float rx, float ry, float rz,
    const float* s_cw1, const float* s_cb1, const float* s_sc, const float* s_sh,
    const short* __restrict__ cw2b, const float (&pc2)[8],
    short* fw, int g, int c16)
{
  bf16x8 a2[2];
  #pragma unroll
  for (int ks = 0; ks < 2; ++ks){
    bf16x8 v;
    #pragma unroll
    for (int j = 0; j < 8; ++j){
      int o = ks*32 + g*8 + j;
      float h = s_cw1[o*3]*rx + s_cw1[o*3+1]*ry + s_cw1[o*3+2]*rz + s_cb1[o];
      h = h * s_sc[o] + s_sh[o];
      h = h / (1.0f + __expf(-h));
      v[j] = bfr(h);
    }
    a2[ks] = v;
  }
  #pragma unroll
  for (int t = 0; t < 8; ++t){
    f32x4 a = (f32x4){0.f,0.f,0.f,0.f};
    #pragma unroll
    for (int ks = 0; ks < 2; ++ks){
      bf16x8 w = *(const bf16x8*)(cw2b + (t*16 + c16)*64 + ks*32 + g*8);
      a = __builtin_amdgcn_mfma_f32_16x16x32_bf16(a2[ks], w, a, 0, 0, 0);
    }
    #pragma unroll
    for (int r = 0; r < 4; ++r)
      fw[(g*4 + r)*264 + 128 + t*16 + c16] = bfr(a[r] + pc2[t]);
  }
}

__device__ __forceinline__ void epilogue_store(
    f32x4 (&acc)[8], const float (&pbf)[8], const float (&pgf)[8], const float (&pef)[8],
    const float (&pal)[8], const float (&pbt)[8],
    int point, int g, int c16, float* __restrict__ out)
{
  float sm[4] = {0,0,0,0}, sq[4] = {0,0,0,0};
  #pragma unroll
  for (int t = 0; t < 8; ++t){
    #pragma unroll
    for (int r = 0; r < 4; ++r){
      float v = acc[t][r] + pbf[t];
      acc[t][r] = v;
      sm[r] += v; sq[r] += v*v;
    }
  }
  #pragma unroll
  for (int mask = 1; mask < 16; mask <<= 1){
    #pragma unroll
    for (int r = 0; r < 4; ++r){ sm[r] += __shfl_xor(sm[r], mask); sq[r] += __shfl_xor(sq[r], mask); }
  }
  #pragma unroll
  for (int r = 0; r < 4; ++r){
    float mean = sm[r] * (1.0f/128.0f);
    float var  = sq[r]*(1.0f/128.0f) - mean*mean;
    float rstd = rsqrtf(var + 1e-5f);
    #pragma unroll
    for (int t = 0; t < 8; ++t){
      float y = (acc[t][r] - mean) * rstd * pgf[t] + pef[t];
      y = y / (1.0f + __expf(-y));
      acc[t][r] = pal[t]*y + pbt[t];
    }
  }
  float sr[4] = {0,0,0,0};
  #pragma unroll
  for (int t = 0; t < 8; ++t){
    #pragma unroll
    for (int r = 0; r < 4; ++r) sr[r] += acc[t][r];
  }
  #pragma unroll
  for (int mask = 1; mask < 16; mask <<= 1){
    #pragma unroll
    for (int r = 0; r < 4; ++r) sr[r] += __shfl_xor(sr[r], mask);
  }
  float mx = fmaxf(fmaxf(sr[0], sr[1]), fmaxf(sr[2], sr[3]));
  mx = fmaxf(mx, __shfl_xor(mx, 16));
  mx = fmaxf(mx, __shfl_xor(mx, 32));
  float e[4]; float se = 0.f;
  #pragma unroll
  for (int r = 0; r < 4; ++r){ e[r] = __expf(sr[r] - mx); se += e[r]; }
  se += __shfl_xor(se, 16);
  se += __shfl_xor(se, 32);
  float inv = 1.0f / se;
  #pragma unroll
  for (int r = 0; r < 4; ++r) e[r] *= inv;
  #pragma unroll
  for (int t = 0; t < 8; ++t){
    float o = e[0]*acc[t][0] + e[1]*acc[t][1] + e[2]*acc[t][2] + e[3]*acc[t][3];
    o += __shfl_xor(o, 16);
    o += __shfl_xor(o, 32);
    if (g == 0) out[point*128 + t*16 + c16] = o;
  }
}

__global__ __launch_bounds__(256) void lga_main_kernel(
    const float* __restrict__ xyz, const float* __restrict__ feats, const int* __restrict__ idx_ws,
    const short* __restrict__ W1T, const short* __restrict__ WfT, const short* __restrict__ cw2b,
    const float* __restrict__ b1, const float* __restrict__ ln1g, const float* __restrict__ ln1b,
    const float* __restrict__ cw1, const float* __restrict__ cb1,
    const float* __restrict__ bnsc, const float* __restrict__ bnsh,
    const float* __restrict__ cb2, const float* __restrict__ bfb,
    const float* __restrict__ lnfg, const float* __restrict__ lnfb,
    const float* __restrict__ alpha, const float* __restrict__ beta,
    float* __restrict__ out)
{
  __shared__ short fuse[4][16][264];     // per-wave buffer, time-shared by the 2 points
  __shared__ float s_cw1[192], s_cb1[64], s_sc[64], s_sh[64];

  int tid = threadIdx.x;
  for (int i = tid; i < 192; i += 256) s_cw1[i] = cw1[i];
  if (tid < 64){ s_cb1[tid] = cb1[tid]; s_sc[tid] = bnsc[tid]; s_sh[tid] = bnsh[tid]; }
  __syncthreads();

  int wv = tid >> 6, lane = tid & 63, g = lane >> 4, c16 = lane & 15;
  int pA = blockIdx.x*8 + wv*2;
  int pB = pA + 1;
  int bbA = pA >> 12, nAi = pA & 4095;
  int bbB = pB >> 12, nBi = pB & 4095;

  int nbA = idx_ws[pA*16 + c16];
  int nbB = idx_ws[pB*16 + c16];

  // gather neighbor features for both points
  const float* frA = feats + (bbA*N_ + nbA)*128;
  const float* frB = feats + (bbB*N_ + nbB)*128;
  bf16x8 a1A[4], a1B[4];
  #pragma unroll
  for (int ks = 0; ks < 4; ++ks){
    f32x4 lo = *(const f32x4*)(frA + ks*32 + g*8);
    f32x4 hi = *(const f32x4*)(frA + ks*32 + g*8 + 4);
    bf16x8 v;
    v[0]=bfr(lo[0]); v[1]=bfr(lo[1]); v[2]=bfr(lo[2]); v[3]=bfr(lo[3]);
    v[4]=bfr(hi[0]); v[5]=bfr(hi[1]); v[6]=bfr(hi[2]); v[7]=bfr(hi[3]);
    a1A[ks] = v;
    lo = *(const f32x4*)(frB + ks*32 + g*8);
    hi = *(const f32x4*)(frB + ks*32 + g*8 + 4);
    v[0]=bfr(lo[0]); v[1]=bfr(lo[1]); v[2]=bfr(lo[2]); v[3]=bfr(lo[3]);
    v[4]=bfr(hi[0]); v[5]=bfr(hi[1]); v[6]=bfr(hi[2]); v[7]=bfr(hi[3]);
    a1B[ks] = v;
  }

  // GEMM1 with shared B fragments
  f32x4 accA[8], accB[8];
  #pragma unroll
  for (int t = 0; t < 8; ++t){ accA[t] = (f32x4){0.f,0.f,0.f,0.f}; accB[t] = (f32x4){0.f,0.f,0.f,0.f}; }
  #pragma unroll
  for (int t = 0; t < 8; ++t){
    #pragma unroll
    for (int ks = 0; ks < 4; ++ks){
      bf16x8 w = *(const bf16x8*)(W1T + (t*16 + c16)*128 + ks*32 + g*8);
      accA[t] = __builtin_amdgcn_mfma_f32_16x16x32_bf16(a1A[ks], w, accA[t], 0, 0, 0);
      accB[t] = __builtin_amdgcn_mfma_f32_16x16x32_bf16(a1B[ks], w, accB[t], 0, 0, 0);
    }
  }

  // LN1/geo params
  float p_b1[8], p_g1[8], p_e1[8], p_c2[8];
  #pragma unroll
  for (int t = 0; t < 8; ++t){
    int col = t*16 + c16;
    p_b1[t] = b1[col]; p_g1[t] = ln1g[col]; p_e1[t] = ln1b[col]; p_c2[t] = cb2[col];
  }

  short* fw = &fuse[wv][0][0];

  // ---- phase A: build concat(tf,geo) for point A, read a3A
  ln_silu_store(accA, p_b1, p_g1, p_e1, fw, g, c16);
  {
    const float* cx = xyz + (bbA*N_ + nAi)*3;
    const float* nx = xyz + (bbA*N_ + nbA)*3;
    geo_store(nx[0]-cx[0], nx[1]-cx[1], nx[2]-cx[2],
              s_cw1, s_cb1, s_sc, s_sh, cw2b, p_c2, fw, g, c16);
  }
  __syncthreads();
  bf16x8 a3A[8];
  #pragma unroll
  for (int ks = 0; ks < 8; ++ks)
    a3A[ks] = *(const bf16x8*)(fw + c16*264 + ks*32 + g*8);
  __syncthreads();

  // ---- phase B: rebuild buffer for point B, read a3B
  ln_silu_store(accB, p_b1, p_g1, p_e1, fw, g, c16);
  {
    const float* cx = xyz + (bbB*N_ + nBi)*3;
    const float* nx = xyz + (bbB*N_ + nbB)*3;
    geo_store(nx[0]-cx[0], nx[1]-cx[1], nx[2]-cx[2],
              s_cw1, s_cb1, s_sc, s_sh, cw2b, p_c2, fw, g, c16);
  }
  __syncthreads();
  bf16x8 a3B[8];
  #pragma unroll
  for (int ks = 0; ks < 8; ++ks)
    a3B[ks] = *(const bf16x8*)(fw + c16*264 + ks*32 + g*8);

  // GEMM3 with shared B fragments
  #pragma unroll
  for (int t = 0; t < 8; ++t){ accA[t] = (f32x4){0.f,0.f,0.f,0.f}; accB[t] = (f32x4){0.f,0.f,0.f,0.f}; }
  #pragma unroll
  for (int t = 0; t < 8; ++t){
    bf16x8 w[8];
    #pragma unroll
    for (int ks = 0; ks < 8; ++ks)
      w[ks] = *(const bf16x8*)(WfT + (t*16 + c16)*256 + ks*32 + g*8);
    #pragma unroll
    for (int ks = 0; ks < 8; ++ks){
      accA[t] = __builtin_amdgcn_mfma_f32_16x16x32_bf16(a3A[ks], w[ks], accA[t], 0, 0, 0);
      accB[t] = __builtin_amdgcn_mfma_f32_16x16x32_bf16(a3B[ks], w[ks], accB[t], 0, 0, 0);
    }
  }

  // epilogue params loaded late to cap register pressure
  float p_bf[8], p_gf[8], p_ef[8], p_al[8], p_bt[8];
  #pragma unroll
  for (int t = 0; t < 8; ++t){
    int col = t*16 + c16;
    p_bf[t] = bfb[col]; p_gf[t] = lnfg[col]; p_ef[t] = lnfb[col];
    p_al[t] = alpha[col]; p_bt[t] = beta[col];
  }
  epilogue_store(accA, p_bf, p_gf, p_ef, p_al, p_bt, pA, g, c16, out);
  epilogue_store(accB, p_bf, p_gf, p_ef, p_al, p_bt, pB, g, c16, out);
}

// ---------------- launch ----------------
extern "C" void kernel_launch(void* const* d_in, const int* in_sizes, int n_in,
                              void* d_out, int out_size, void* d_ws, size_t ws_size,
                              hipStream_t stream)
{
  (void)in_sizes; (void)n_in; (void)out_size; (void)ws_size;
  const float* xyz   = (const float*)d_in[0];
  const float* feats = (const float*)d_in[1];
  const float* W1    = (const float*)d_in[2];
  const float* b1    = (const float*)d_in[3];
  const float* ln1g  = (const float*)d_in[4];
  const float* ln1b  = (const float*)d_in[5];
  const float* cw1   = (const float*)d_in[6];
  const float* cb1   = (const float*)d_in[7];
  const float* bng   = (const float*)d_in[8];
  const float* bnb   = (const float*)d_in[9];
  const float* cw2   = (const float*)d_in[10];
  const float* cb2   = (const float*)d_in[11];
  const float* Wf    = (const float*)d_in[12];
  const float* bfb   = (const float*)d_in[13];
  const float* lnfg  = (const float*)d_in[14];
  const float* lnfb  = (const float*)d_in[15];
  const float* alpha = (const float*)d_in[16];
  const float* beta  = (const float*)d_in[17];

  char* ws = (char*)d_ws;
  int*   idx   = (int*)  (ws);                 // 32768*16*4 = 2,097,152 B
  float* stats = (float*)(ws + 2097152);       // 16 floats
  float* bnsc  = (float*)(ws + 2097216);       // 64 floats
  float* bnsh  = (float*)(ws + 2097472);       // 64 floats
  short* W1T   = (short*)(ws + 2097728);       // 32 KB
  short* WfT   = (short*)(ws + 2130496);       // 64 KB
  short* cw2b  = (short*)(ws + 2196032);       // 16 KB

  hipLaunchKernelGGL(prep_kernel, dim3(225), dim3(256), 0, stream,
                     W1, Wf, cw2, W1T, WfT, cw2b, stats);
  hipLaunchKernelGGL(knn_kernel, dim3(256), dim3(1024), 0, stream,
                     xyz, idx, stats);
  hipLaunchKernelGGL(bn_finalize_kernel, dim3(1), dim3(64), 0, stream,
                     stats, cw1, cb1, bng, bnb, bnsc, bnsh);
  hipLaunchKernelGGL(lga_main_kernel, dim3(4096), dim3(256), 0, stream,
                     xyz, feats, idx, W1T, WfT, cw2b,
                     b1, ln1g, ln1b, cw1, cb1, bnsc, bnsh,
                     cb2, bfb, lnfg, lnfb, alpha, beta,
                     (float*)d_out);
}